// Round 3
// baseline (269.730 us; speedup 1.0000x reference)
//
#include <hip/hip_runtime.h>
#include <hip/hip_bf16.h>

// Problem constants (from reference): N=100000, E=3200000, C=4, H=64
// Float inputs are float32; edge_index int32; output concat(pm10_next, delta) f32.
#define HID 64
#define EPSV 1e-8f
#define BLK 256
#define RPT 4   // edges per thread

// Edge kernel: per edge build feat[10], run 64x10 MLP + relu, fold the linear
// head to a scalar s_e = sum_h head_w[h]*relu_h, atomic-add into delta_acc[dst].
// KEY (R3): unsafeAtomicAdd -> native global_atomic_add_f32 (no CAS retry loop).
// d_ws is coarse-grained device memory, so the HW fp atomic is safe.
__global__ __launch_bounds__(BLK) void edge_kernel(
    const float4* __restrict__ x,       // N x 4 f32 rows (16B)
    const float2* __restrict__ pos,     // N x 2 f32 rows (8B)
    const float*  __restrict__ mlp_w,   // 64*10 f32, row-major [h][j]
    const float*  __restrict__ mlp_b,   // 64 f32
    const float*  __restrict__ head_w,  // 64 f32
    const int*    __restrict__ srcs,
    const int*    __restrict__ dsts,
    float* __restrict__ delta_acc,
    int E)
{
    // Weight rows in LDS as [w0..w9, bias, head_w] = 3 x float4 per h.
    // Reads in the h-loop are wave-uniform -> LDS broadcast, conflict-free.
    __shared__ float4 wrow[HID * 3];
    int tid = threadIdx.x;
    for (int h = tid; h < HID; h += BLK) {
        const float* wr = mlp_w + h * 10;
        float4 a, b, c;
        a.x = wr[0]; a.y = wr[1]; a.z = wr[2]; a.w = wr[3];
        b.x = wr[4]; b.y = wr[5]; b.z = wr[6]; b.w = wr[7];
        c.x = wr[8]; c.y = wr[9]; c.z = mlp_b[h]; c.w = head_w[h];
        wrow[h * 3 + 0] = a;
        wrow[h * 3 + 1] = b;
        wrow[h * 3 + 2] = c;
    }
    __syncthreads();

    long base = (long)blockIdx.x * (BLK * RPT) + tid;  // r-th edge at base+r*BLK (coalesced)

    float f[RPT][10];
    int   edst[RPT];
    bool  valid[RPT];

    #pragma unroll
    for (int r = 0; r < RPT; r++) {
        long e = base + (long)r * BLK;
        bool ok = (e < (long)E);
        valid[r] = ok;
        long ee = ok ? e : 0;
        int s = srcs[ee];
        int d = dsts[ee];
        edst[r] = d;
        float4 xs = x[s];
        float4 xd = x[d];
        float2 ps = pos[s];
        float2 pd = pos[d];
        float d0 = ps.x - pd.x;
        float d1 = ps.y - pd.y;
        float dist = sqrtf(fmaf(d0, d0, fmaf(d1, d1, EPSV)));
        float inv = 1.0f / dist;
        float wind = (xs.y * d0 + xs.z * d1) * inv;  // u10[src]*dhat0 + v10[src]*dhat1
        f[r][0] = xd.x;
        f[r][1] = xd.y;
        f[r][2] = xd.z;
        f[r][3] = xd.w;
        f[r][4] = xs.x;
        f[r][5] = xs.y;
        f[r][6] = xs.z;
        f[r][7] = xs.w;
        f[r][8] = wind;
        f[r][9] = dist;
    }

    float sacc[RPT];
    #pragma unroll
    for (int r = 0; r < RPT; r++) sacc[r] = 0.0f;

    for (int h = 0; h < HID; h++) {
        float4 w0 = wrow[h * 3 + 0];
        float4 w1 = wrow[h * 3 + 1];
        float4 w2 = wrow[h * 3 + 2];
        #pragma unroll
        for (int r = 0; r < RPT; r++) {
            float a = w2.z;
            a = fmaf(w0.x, f[r][0], a);
            a = fmaf(w0.y, f[r][1], a);
            a = fmaf(w0.z, f[r][2], a);
            a = fmaf(w0.w, f[r][3], a);
            a = fmaf(w1.x, f[r][4], a);
            a = fmaf(w1.y, f[r][5], a);
            a = fmaf(w1.z, f[r][6], a);
            a = fmaf(w1.w, f[r][7], a);
            a = fmaf(w2.x, f[r][8], a);
            a = fmaf(w2.y, f[r][9], a);
            a = fmaxf(a, 0.0f);
            sacc[r] = fmaf(w2.w, a, sacc[r]);
        }
    }

    #pragma unroll
    for (int r = 0; r < RPT; r++) {
        if (valid[r]) {
            // Native HW fp32 atomic (global_atomic_add_f32), fire-and-forget.
            unsafeAtomicAdd(&delta_acc[edst[r]], sacc[r]);
        }
    }
}

// Node kernel: delta = acc + head_b; pm10_next = softplus(x0 + delta).
__global__ __launch_bounds__(BLK) void node_kernel(
    const float4* __restrict__ x,
    const float*  __restrict__ delta_acc,
    const float*  __restrict__ head_b,
    float* __restrict__ out,
    int N)
{
    int n = blockIdx.x * BLK + threadIdx.x;
    if (n >= N) return;
    float delta = delta_acc[n] + head_b[0];
    float v = x[n].x + delta;
    // stable softplus: max(v,0) + log1p(exp(-|v|))
    float sp = fmaxf(v, 0.0f) + log1pf(expf(-fabsf(v)));
    out[n] = sp;
    out[N + n] = delta;
}

extern "C" void kernel_launch(void* const* d_in, const int* in_sizes, int n_in,
                              void* d_out, int out_size, void* d_ws, size_t ws_size,
                              hipStream_t stream) {
    const float4* x      = (const float4*)d_in[0];
    const float2* pos    = (const float2*)d_in[1];
    const float*  mlp_w  = (const float*)d_in[2];
    const float*  mlp_b  = (const float*)d_in[3];
    const float*  head_w = (const float*)d_in[4];
    const float*  head_b = (const float*)d_in[5];
    const int*    ei     = (const int*)d_in[6];

    int N = in_sizes[0] / 4;   // 100000
    int E = in_sizes[6] / 2;   // 3200000
    const int* srcs = ei;
    const int* dsts = ei + E;

    float* delta_acc = (float*)d_ws;
    hipMemsetAsync(delta_acc, 0, (size_t)N * sizeof(float), stream);

    int edge_blocks = (E + BLK * RPT - 1) / (BLK * RPT);
    edge_kernel<<<edge_blocks, BLK, 0, stream>>>(x, pos, mlp_w, mlp_b, head_w,
                                                 srcs, dsts, delta_acc, E);

    int node_blocks = (N + BLK - 1) / BLK;
    node_kernel<<<node_blocks, BLK, 0, stream>>>(x, delta_acc, head_b,
                                                 (float*)d_out, N);
}

// Round 4
// 230.693 us; speedup vs baseline: 1.1692x; 1.1692x over previous
//
#include <hip/hip_runtime.h>
#include <hip/hip_bf16.h>

// N=100000, E=3200000, C=4, H=64. f32 inputs; edge_index int32;
// output concat(pm10_next[N], delta[N]) f32.
//
// R4 structure: global f32 atomics are rate-limited (~1/cyc/XCD, measured
// 0.85/cyc/XCD in R3 with WRITE_SIZE == E*32B). So: bucket edges by dst
// (256 nodes/bucket), LDS-privatized reduction per bucket, ~0.16 global
// atomics/edge instead of 1.0.

#define HID    64
#define EPSV   1e-8f
#define BSHIFT 8
#define BNODES 256          // nodes per bucket
#define CAP    10240        // slots per bucket (mean ~8184, +23 sigma)
#define MAXB   512          // max buckets supported by LDS arrays in scatter
#define NB1    256          // scatter blocks
#define BLK1   256
#define BLK2   512
#define OVF_CAP 65536

// ---------- shared device helpers ----------

__device__ __forceinline__ void load_feat(const float4* __restrict__ x,
                                          const float2* __restrict__ pos,
                                          int s, int d, float* f) {
    float4 xs = x[s];
    float4 xd = x[d];
    float2 ps = pos[s];
    float2 pd = pos[d];
    float d0 = ps.x - pd.x;
    float d1 = ps.y - pd.y;
    float dist = sqrtf(fmaf(d0, d0, fmaf(d1, d1, EPSV)));
    float inv = 1.0f / dist;
    float wind = (xs.y * d0 + xs.z * d1) * inv;
    f[0] = xd.x; f[1] = xd.y; f[2] = xd.z; f[3] = xd.w;
    f[4] = xs.x; f[5] = xs.y; f[6] = xs.z; f[7] = xs.w;
    f[8] = wind; f[9] = dist;
}

// wrow[h*3..h*3+2] = [w0..w9, bias, head_w] per hidden unit
template <int BLK>
__device__ __forceinline__ void stage_weights(const float* __restrict__ mlp_w,
                                              const float* __restrict__ mlp_b,
                                              const float* __restrict__ head_w,
                                              float4* wrow) {
    for (int h = threadIdx.x; h < HID; h += BLK) {
        const float* wr = mlp_w + h * 10;
        float4 a, b, c;
        a.x = wr[0]; a.y = wr[1]; a.z = wr[2]; a.w = wr[3];
        b.x = wr[4]; b.y = wr[5]; b.z = wr[6]; b.w = wr[7];
        c.x = wr[8]; c.y = wr[9]; c.z = mlp_b[h]; c.w = head_w[h];
        wrow[h * 3 + 0] = a;
        wrow[h * 3 + 1] = b;
        wrow[h * 3 + 2] = c;
    }
}

__device__ __forceinline__ float mlp_scalar(const float4* wrow, const float* f) {
    float sacc = 0.0f;
    for (int h = 0; h < HID; h++) {
        float4 w0 = wrow[h * 3 + 0];
        float4 w1 = wrow[h * 3 + 1];
        float4 w2 = wrow[h * 3 + 2];
        float a = w2.z;
        a = fmaf(w0.x, f[0], a); a = fmaf(w0.y, f[1], a);
        a = fmaf(w0.z, f[2], a); a = fmaf(w0.w, f[3], a);
        a = fmaf(w1.x, f[4], a); a = fmaf(w1.y, f[5], a);
        a = fmaf(w1.z, f[6], a); a = fmaf(w1.w, f[7], a);
        a = fmaf(w2.x, f[8], a); a = fmaf(w2.y, f[9], a);
        a = fmaxf(a, 0.0f);
        sacc = fmaf(w2.w, a, sacc);
    }
    return sacc;
}

// ---------- fast path kernels ----------

__global__ void init_kernel(int* g_ptr, int* ovf_cnt, int B) {
    int t = blockIdx.x * blockDim.x + threadIdx.x;
    if (t < B) g_ptr[t] = t * CAP;
    if (t == 0) *ovf_cnt = 0;
}

// Bucket edges by dst>>8. One global int atomic per (block,bucket) for space
// reservation; per-edge ranks via LDS atomics.
__global__ __launch_bounds__(BLK1) void scatter_kernel(
    const int* __restrict__ srcs, const int* __restrict__ dsts,
    int E, int B, int chunk,
    int* g_ptr, int2* __restrict__ sorted, int2* __restrict__ ovf, int* ovf_cnt)
{
    __shared__ int hist[MAXB];
    __shared__ int base[MAXB];
    __shared__ int run[MAXB];
    int tid = threadIdx.x;
    int lo = blockIdx.x * chunk;
    int hi = min(E, lo + chunk);
    for (int b = tid; b < B; b += BLK1) { hist[b] = 0; run[b] = 0; }
    __syncthreads();
    for (int e = lo + tid; e < hi; e += BLK1)
        atomicAdd(&hist[dsts[e] >> BSHIFT], 1);
    __syncthreads();
    for (int b = tid; b < B; b += BLK1) {
        int h = hist[b];
        base[b] = (h > 0) ? atomicAdd(&g_ptr[b], h) : 0;
    }
    __syncthreads();
    for (int e = lo + tid; e < hi; e += BLK1) {
        int d = dsts[e];
        int s = srcs[e];
        int b = d >> BSHIFT;
        int r = atomicAdd(&run[b], 1);
        int slot = base[b] + r;
        if (slot < (b + 1) * CAP) {
            sorted[slot] = make_int2(s, d);
        } else {  // statistically never (CAP = mean + 23 sigma); robust anyway
            int o = atomicAdd(ovf_cnt, 1);
            if (o < OVF_CAP) ovf[o] = make_int2(s, d);
        }
    }
}

// 2 blocks per bucket. Coalesced reads of bucketed edges, RPT=4 MLP,
// LDS f32-atomic accumulation over the bucket's 256-node range, then
// <=256 global atomics per block.
__global__ __launch_bounds__(BLK2) void bucket_kernel(
    const float4* __restrict__ x, const float2* __restrict__ pos,
    const float* __restrict__ mlp_w, const float* __restrict__ mlp_b,
    const float* __restrict__ head_w,
    const int2* __restrict__ sorted, const int* __restrict__ g_ptr,
    float* __restrict__ delta, int N)
{
    __shared__ float4 wrow[HID * 3];
    __shared__ float acc[BNODES];
    int tid = threadIdx.x;
    stage_weights<BLK2>(mlp_w, mlp_b, head_w, wrow);
    for (int t = tid; t < BNODES; t += BLK2) acc[t] = 0.0f;
    __syncthreads();

    int b = blockIdx.x >> 1;
    int half = blockIdx.x & 1;
    int cnt = g_ptr[b] - b * CAP;
    cnt = min(cnt, CAP);
    int mid = cnt >> 1;
    int e0 = half ? mid : 0;
    int e1 = half ? cnt : mid;
    const int2* se = sorted + (size_t)b * CAP;
    int nbase = b * BNODES;

    for (int i0 = e0; i0 < e1; i0 += 4 * BLK2) {
        float f[4][10];
        int   off4[4];
        bool  val4[4];
        #pragma unroll
        for (int r = 0; r < 4; r++) {
            int i = i0 + r * BLK2 + tid;
            bool ok = (i < e1);
            val4[r] = ok;
            int2 sd = se[ok ? i : e0];
            load_feat(x, pos, sd.x, sd.y, f[r]);
            off4[r] = sd.y - nbase;   // in [0, 256) by bucket construction
        }
        float sacc[4] = {0.f, 0.f, 0.f, 0.f};
        for (int h = 0; h < HID; h++) {
            float4 w0 = wrow[h * 3 + 0];
            float4 w1 = wrow[h * 3 + 1];
            float4 w2 = wrow[h * 3 + 2];
            #pragma unroll
            for (int r = 0; r < 4; r++) {
                float a = w2.z;
                a = fmaf(w0.x, f[r][0], a); a = fmaf(w0.y, f[r][1], a);
                a = fmaf(w0.z, f[r][2], a); a = fmaf(w0.w, f[r][3], a);
                a = fmaf(w1.x, f[r][4], a); a = fmaf(w1.y, f[r][5], a);
                a = fmaf(w1.z, f[r][6], a); a = fmaf(w1.w, f[r][7], a);
                a = fmaf(w2.x, f[r][8], a); a = fmaf(w2.y, f[r][9], a);
                a = fmaxf(a, 0.0f);
                sacc[r] = fmaf(w2.w, a, sacc[r]);
            }
        }
        #pragma unroll
        for (int r = 0; r < 4; r++) {
            if (val4[r]) atomicAdd(&acc[off4[r]], sacc[r]);  // LDS atomic, on-chip
        }
    }
    __syncthreads();
    for (int t = tid; t < BNODES; t += BLK2) {
        float v = acc[t];
        int n = nbase + t;
        if (v != 0.0f && n < N) unsafeAtomicAdd(&delta[n], v);
    }
}

// Cleanup for (statistically impossible) bucket overflow; usually 0 edges.
__global__ __launch_bounds__(256) void ovf_kernel(
    const float4* __restrict__ x, const float2* __restrict__ pos,
    const float* __restrict__ mlp_w, const float* __restrict__ mlp_b,
    const float* __restrict__ head_w,
    const int2* __restrict__ ovf, const int* __restrict__ ovf_cnt,
    float* __restrict__ delta)
{
    __shared__ float4 wrow[HID * 3];
    stage_weights<256>(mlp_w, mlp_b, head_w, wrow);
    __syncthreads();
    int cnt = min(*ovf_cnt, OVF_CAP);
    for (int i = blockIdx.x * blockDim.x + threadIdx.x; i < cnt;
         i += gridDim.x * blockDim.x) {
        int2 sd = ovf[i];
        float f[10];
        load_feat(x, pos, sd.x, sd.y, f);
        unsafeAtomicAdd(&delta[sd.y], mlp_scalar(wrow, f));
    }
}

// ---------- fallback path (ws too small): R3 kernel ----------

#define RPT 4
__global__ __launch_bounds__(256) void edge_kernel_fallback(
    const float4* __restrict__ x, const float2* __restrict__ pos,
    const float* __restrict__ mlp_w, const float* __restrict__ mlp_b,
    const float* __restrict__ head_w,
    const int* __restrict__ srcs, const int* __restrict__ dsts,
    float* __restrict__ delta_acc, int E)
{
    __shared__ float4 wrow[HID * 3];
    stage_weights<256>(mlp_w, mlp_b, head_w, wrow);
    __syncthreads();
    int tid = threadIdx.x;
    long base = (long)blockIdx.x * (256 * RPT) + tid;
    float f[RPT][10];
    int edst[RPT];
    bool valid[RPT];
    #pragma unroll
    for (int r = 0; r < RPT; r++) {
        long e = base + (long)r * 256;
        bool ok = (e < (long)E);
        valid[r] = ok;
        long ee = ok ? e : 0;
        int s = srcs[ee], d = dsts[ee];
        edst[r] = d;
        load_feat(x, pos, s, d, f[r]);
    }
    float sacc[RPT] = {0.f, 0.f, 0.f, 0.f};
    for (int h = 0; h < HID; h++) {
        float4 w0 = wrow[h * 3 + 0];
        float4 w1 = wrow[h * 3 + 1];
        float4 w2 = wrow[h * 3 + 2];
        #pragma unroll
        for (int r = 0; r < RPT; r++) {
            float a = w2.z;
            a = fmaf(w0.x, f[r][0], a); a = fmaf(w0.y, f[r][1], a);
            a = fmaf(w0.z, f[r][2], a); a = fmaf(w0.w, f[r][3], a);
            a = fmaf(w1.x, f[r][4], a); a = fmaf(w1.y, f[r][5], a);
            a = fmaf(w1.z, f[r][6], a); a = fmaf(w1.w, f[r][7], a);
            a = fmaf(w2.x, f[r][8], a); a = fmaf(w2.y, f[r][9], a);
            a = fmaxf(a, 0.0f);
            sacc[r] = fmaf(w2.w, a, sacc[r]);
        }
    }
    #pragma unroll
    for (int r = 0; r < RPT; r++)
        if (valid[r]) unsafeAtomicAdd(&delta_acc[edst[r]], sacc[r]);
}

// ---------- epilogue ----------

__global__ __launch_bounds__(256) void node_kernel(
    const float4* __restrict__ x, const float* __restrict__ delta_acc,
    const float* __restrict__ head_b, float* __restrict__ out, int N)
{
    int n = blockIdx.x * 256 + threadIdx.x;
    if (n >= N) return;
    float delta = delta_acc[n] + head_b[0];
    float v = x[n].x + delta;
    float sp = fmaxf(v, 0.0f) + log1pf(expf(-fabsf(v)));
    out[n] = sp;
    out[N + n] = delta;
}

// ---------- host ----------

static inline size_t align_up(size_t v, size_t a) { return (v + a - 1) & ~(a - 1); }

extern "C" void kernel_launch(void* const* d_in, const int* in_sizes, int n_in,
                              void* d_out, int out_size, void* d_ws, size_t ws_size,
                              hipStream_t stream) {
    const float4* x      = (const float4*)d_in[0];
    const float2* pos    = (const float2*)d_in[1];
    const float*  mlp_w  = (const float*)d_in[2];
    const float*  mlp_b  = (const float*)d_in[3];
    const float*  head_w = (const float*)d_in[4];
    const float*  head_b = (const float*)d_in[5];
    const int*    ei     = (const int*)d_in[6];

    int N = in_sizes[0] / 4;   // 100000
    int E = in_sizes[6] / 2;   // 3200000
    const int* srcs = ei;
    const int* dsts = ei + E;
    int B = (N + BNODES - 1) / BNODES;   // 391

    // ws layout
    size_t off = 0;
    float* delta = (float*)((char*)d_ws + off); off = align_up(off + (size_t)N * 4, 256);
    int* g_ptr   = (int*)((char*)d_ws + off);   off = align_up(off + (size_t)B * 4, 256);
    int* ovf_cnt = (int*)((char*)d_ws + off);   off = align_up(off + 64, 256);
    int2* ovf    = (int2*)((char*)d_ws + off);  off = align_up(off + (size_t)OVF_CAP * 8, 256);
    int2* sorted = (int2*)((char*)d_ws + off);  off = align_up(off + (size_t)B * CAP * 8, 256);
    bool fast = (off <= ws_size) && (B <= MAXB);

    hipMemsetAsync(delta, 0, (size_t)N * sizeof(float), stream);

    if (fast) {
        init_kernel<<<(B + 255) / 256, 256, 0, stream>>>(g_ptr, ovf_cnt, B);
        int chunk = (E + NB1 - 1) / NB1;
        scatter_kernel<<<NB1, BLK1, 0, stream>>>(srcs, dsts, E, B, chunk,
                                                 g_ptr, sorted, ovf, ovf_cnt);
        bucket_kernel<<<2 * B, BLK2, 0, stream>>>(x, pos, mlp_w, mlp_b, head_w,
                                                  sorted, g_ptr, delta, N);
        ovf_kernel<<<16, 256, 0, stream>>>(x, pos, mlp_w, mlp_b, head_w,
                                           ovf, ovf_cnt, delta);
    } else {
        int edge_blocks = (E + 256 * RPT - 1) / (256 * RPT);
        edge_kernel_fallback<<<edge_blocks, 256, 0, stream>>>(
            x, pos, mlp_w, mlp_b, head_w, srcs, dsts, delta, E);
    }

    node_kernel<<<(N + 255) / 256, 256, 0, stream>>>(x, delta, head_b,
                                                     (float*)d_out, N);
}

// Round 5
// 226.371 us; speedup vs baseline: 1.1915x; 1.0191x over previous
//
#include <hip/hip_runtime.h>
#include <hip/hip_bf16.h>

// N=100000, E=3200000, C=4, H=64. f32 inputs; edge_index int32;
// output concat(pm10_next[N], delta[N]) f32.
//
// R5 structure:
//  init      : zero pair-packed bucket counters + ovf counter
//  fused     : per chunk: (a) LDS histogram of dst>>8, (b) u64-paired global
//              reservation (2 buckets/atomic), (c) compute s_e (MLP, weights
//              read via wave-uniform scalar loads - K$ not LDS) and scatter
//              packed payload (f32 value, low 8 mantissa bits = dst&255)
//  ovf       : statistically-never overflow edges -> delta_extra atomics
//  reduce    : 1 block per 256-node bucket: ds_add_f32 accumulate payloads,
//              fused softplus epilogue, plain coalesced stores. No atomics.

#define HID    64
#define EPSV   1e-8f
#define BSHIFT 8
#define BNODES 256
#define CAP    10240        // mean 8192, sigma ~90 -> +22 sigma
#define MAXB   512
#define NB     512          // fused grid
#define BLK    512          // fused block
#define RPT    4
#define OVF_CAP 65536

__device__ __forceinline__ void load_feat(const float4* __restrict__ x,
                                          const float2* __restrict__ pos,
                                          int s, int d, float* f) {
    float4 xs = x[s];
    float4 xd = x[d];
    float2 ps = pos[s];
    float2 pd = pos[d];
    float d0 = ps.x - pd.x;
    float d1 = ps.y - pd.y;
    float dist = sqrtf(fmaf(d0, d0, fmaf(d1, d1, EPSV)));
    float inv = 1.0f / dist;
    float wind = (xs.y * d0 + xs.z * d1) * inv;
    f[0] = xd.x; f[1] = xd.y; f[2] = xd.z; f[3] = xd.w;
    f[4] = xs.x; f[5] = xs.y; f[6] = xs.z; f[7] = xs.w;
    f[8] = wind; f[9] = dist;
}

__global__ void init_kernel(unsigned long long* g_ptr64, int* ovf_cnt, int PB) {
    int t = blockIdx.x * blockDim.x + threadIdx.x;
    if (t < PB) g_ptr64[t] = 0ull;
    if (t == 0) *ovf_cnt = 0;
}

// ---------------- fused compute + scatter ----------------
__global__ __launch_bounds__(BLK) void fused_kernel(
    const float4* __restrict__ x, const float2* __restrict__ pos,
    const float* __restrict__ mlp_w, const float* __restrict__ mlp_b,
    const float* __restrict__ head_w,
    const int* __restrict__ srcs, const int* __restrict__ dsts,
    int E, int B, int chunk,
    unsigned long long* g_ptr64, unsigned int* __restrict__ sorted,
    int2* __restrict__ ovf, int* ovf_cnt)
{
    __shared__ int hist[MAXB];
    __shared__ int base[MAXB];
    __shared__ int run[MAXB];
    int tid = threadIdx.x;
    int lo = blockIdx.x * chunk;
    int hi = min(E, lo + chunk);

    for (int b = tid; b < B; b += BLK) { hist[b] = 0; run[b] = 0; }
    __syncthreads();
    for (int e = lo + tid; e < hi; e += BLK)
        atomicAdd(&hist[dsts[e] >> BSHIFT], 1);
    __syncthreads();
    int PB = (B + 1) >> 1;
    for (int p = tid; p < PB; p += BLK) {
        int b0 = 2 * p, b1 = 2 * p + 1;
        unsigned long long h0 = (unsigned int)hist[b0];
        unsigned long long h1 = (b1 < B) ? (unsigned int)hist[b1] : 0ull;
        unsigned long long comb = h0 | (h1 << 32);
        unsigned long long old = 0ull;
        if (comb) old = atomicAdd(&g_ptr64[p], comb);
        base[b0] = (int)(old & 0xffffffffull);
        if (b1 < B) base[b1] = (int)(old >> 32);
    }
    __syncthreads();

    for (int i0 = lo; i0 < hi; i0 += RPT * BLK) {
        float f[RPT][10];
        int   ed[RPT];
        bool  val[RPT];
        #pragma unroll
        for (int r = 0; r < RPT; r++) {
            int e = i0 + r * BLK + tid;
            bool ok = (e < hi);
            val[r] = ok;
            int ee = ok ? e : lo;
            int s = srcs[ee];
            int d = dsts[ee];
            ed[r] = d;
            load_feat(x, pos, s, d, f[r]);
        }

        float sacc[RPT];
        #pragma unroll
        for (int r = 0; r < RPT; r++) sacc[r] = 0.0f;

        // Weights read straight from global with wave-uniform indices:
        // compiler emits s_load via constant cache (SMEM pipe). Keeps the
        // DS pipe free for the rank atomics; re-reads (if the scheduler
        // splits the r-loop) are K$ hits, not LDS traffic.
        for (int h = 0; h < HID; h++) {
            const float* wr = mlp_w + h * 10;
            float w0 = wr[0], w1 = wr[1], w2 = wr[2], w3 = wr[3], w4 = wr[4];
            float w5 = wr[5], w6 = wr[6], w7 = wr[7], w8 = wr[8], w9 = wr[9];
            float bb = mlp_b[h];
            float hw = head_w[h];
            #pragma unroll
            for (int r = 0; r < RPT; r++) {
                float a = bb;
                a = fmaf(w0, f[r][0], a); a = fmaf(w1, f[r][1], a);
                a = fmaf(w2, f[r][2], a); a = fmaf(w3, f[r][3], a);
                a = fmaf(w4, f[r][4], a); a = fmaf(w5, f[r][5], a);
                a = fmaf(w6, f[r][6], a); a = fmaf(w7, f[r][7], a);
                a = fmaf(w8, f[r][8], a); a = fmaf(w9, f[r][9], a);
                a = fmaxf(a, 0.0f);
                sacc[r] = fmaf(hw, a, sacc[r]);
            }
        }

        #pragma unroll
        for (int r = 0; r < RPT; r++) {
            if (val[r]) {
                int d = ed[r];
                int b = d >> BSHIFT;
                int rk = atomicAdd(&run[b], 1);     // LDS, on-chip
                int rel = base[b] + rk;
                unsigned int pay = (__float_as_uint(sacc[r]) & 0xffffff00u)
                                 | (unsigned int)(d & 255);
                if (rel < CAP) {
                    sorted[(size_t)b * CAP + rel] = pay;
                } else {
                    int o = atomicAdd(ovf_cnt, 1);
                    if (o < OVF_CAP) ovf[o] = make_int2(d, (int)pay);
                }
            }
        }
    }
}

// ---------------- overflow cleanup (normally 0 edges) ----------------
__global__ __launch_bounds__(256) void ovf_kernel(
    const int2* __restrict__ ovf, const int* __restrict__ ovf_cnt,
    float* __restrict__ delta_extra)
{
    int cnt = min(*ovf_cnt, OVF_CAP);
    for (int i = blockIdx.x * blockDim.x + threadIdx.x; i < cnt;
         i += gridDim.x * blockDim.x) {
        int2 dp = ovf[i];
        float v = __uint_as_float(((unsigned int)dp.y) & 0xffffff00u);
        unsafeAtomicAdd(&delta_extra[dp.x], v);
    }
}

// ---------------- reduce + node epilogue ----------------
__global__ __launch_bounds__(BNODES) void reduce_kernel(
    const float* __restrict__ xf,             // x as flat f32, stride 4
    const unsigned long long* __restrict__ g_ptr64,
    const unsigned int* __restrict__ sorted,
    const float* __restrict__ delta_extra,
    const float* __restrict__ head_b,
    float* __restrict__ out, int N)
{
    __shared__ float acc[BNODES];
    int b = blockIdx.x;
    int tid = threadIdx.x;
    acc[tid] = 0.0f;
    __syncthreads();
    unsigned long long gp = g_ptr64[b >> 1];
    int cnt = (b & 1) ? (int)(gp >> 32) : (int)(gp & 0xffffffffull);
    cnt = min(cnt, CAP);
    const unsigned int* sp = sorted + (size_t)b * CAP;
    for (int i = tid; i < cnt; i += BNODES) {
        unsigned int u = sp[i];
        atomicAdd(&acc[u & 255u], __uint_as_float(u & 0xffffff00u));  // ds_add_f32
    }
    __syncthreads();
    int n = b * BNODES + tid;
    if (n < N) {
        float delta = acc[tid] + delta_extra[n] + head_b[0];
        float v = xf[4 * n] + delta;
        float sp2 = fmaxf(v, 0.0f) + log1pf(expf(-fabsf(v)));
        out[n] = sp2;
        out[N + n] = delta;
    }
}

// ---------------- fallback path (ws too small) ----------------
__global__ __launch_bounds__(256) void edge_kernel_fallback(
    const float4* __restrict__ x, const float2* __restrict__ pos,
    const float* __restrict__ mlp_w, const float* __restrict__ mlp_b,
    const float* __restrict__ head_w,
    const int* __restrict__ srcs, const int* __restrict__ dsts,
    float* __restrict__ delta_acc, int E)
{
    int tid = threadIdx.x;
    long b0 = (long)blockIdx.x * (256 * RPT) + tid;
    float f[RPT][10];
    int edst[RPT];
    bool valid[RPT];
    #pragma unroll
    for (int r = 0; r < RPT; r++) {
        long e = b0 + (long)r * 256;
        bool ok = (e < (long)E);
        valid[r] = ok;
        long ee = ok ? e : 0;
        int s = srcs[ee], d = dsts[ee];
        edst[r] = d;
        load_feat(x, pos, s, d, f[r]);
    }
    float sacc[RPT] = {0.f, 0.f, 0.f, 0.f};
    for (int h = 0; h < HID; h++) {
        const float* wr = mlp_w + h * 10;
        float w0 = wr[0], w1 = wr[1], w2 = wr[2], w3 = wr[3], w4 = wr[4];
        float w5 = wr[5], w6 = wr[6], w7 = wr[7], w8 = wr[8], w9 = wr[9];
        float bb = mlp_b[h], hw = head_w[h];
        #pragma unroll
        for (int r = 0; r < RPT; r++) {
            float a = bb;
            a = fmaf(w0, f[r][0], a); a = fmaf(w1, f[r][1], a);
            a = fmaf(w2, f[r][2], a); a = fmaf(w3, f[r][3], a);
            a = fmaf(w4, f[r][4], a); a = fmaf(w5, f[r][5], a);
            a = fmaf(w6, f[r][6], a); a = fmaf(w7, f[r][7], a);
            a = fmaf(w8, f[r][8], a); a = fmaf(w9, f[r][9], a);
            a = fmaxf(a, 0.0f);
            sacc[r] = fmaf(hw, a, sacc[r]);
        }
    }
    #pragma unroll
    for (int r = 0; r < RPT; r++)
        if (valid[r]) unsafeAtomicAdd(&delta_acc[edst[r]], sacc[r]);
}

__global__ __launch_bounds__(256) void node_kernel_fallback(
    const float* __restrict__ xf, const float* __restrict__ delta_acc,
    const float* __restrict__ head_b, float* __restrict__ out, int N)
{
    int n = blockIdx.x * 256 + threadIdx.x;
    if (n >= N) return;
    float delta = delta_acc[n] + head_b[0];
    float v = xf[4 * n] + delta;
    float sp = fmaxf(v, 0.0f) + log1pf(expf(-fabsf(v)));
    out[n] = sp;
    out[N + n] = delta;
}

// ---------------- host ----------------
static inline size_t align_up(size_t v, size_t a) { return (v + a - 1) & ~(a - 1); }

extern "C" void kernel_launch(void* const* d_in, const int* in_sizes, int n_in,
                              void* d_out, int out_size, void* d_ws, size_t ws_size,
                              hipStream_t stream) {
    const float4* x      = (const float4*)d_in[0];
    const float2* pos    = (const float2*)d_in[1];
    const float*  mlp_w  = (const float*)d_in[2];
    const float*  mlp_b  = (const float*)d_in[3];
    const float*  head_w = (const float*)d_in[4];
    const float*  head_b = (const float*)d_in[5];
    const int*    ei     = (const int*)d_in[6];

    int N = in_sizes[0] / 4;   // 100000
    int E = in_sizes[6] / 2;   // 3200000
    const int* srcs = ei;
    const int* dsts = ei + E;
    int B  = (N + BNODES - 1) / BNODES;   // 391
    int PB = (B + 1) >> 1;                // 196

    size_t off = 0;
    float* delta_extra = (float*)((char*)d_ws + off);
    off = align_up(off + (size_t)N * 4, 256);
    unsigned long long* g_ptr64 = (unsigned long long*)((char*)d_ws + off);
    off = align_up(off + (size_t)PB * 8, 256);
    int* ovf_cnt = (int*)((char*)d_ws + off);
    off = align_up(off + 64, 256);
    int2* ovf = (int2*)((char*)d_ws + off);
    off = align_up(off + (size_t)OVF_CAP * 8, 256);
    unsigned int* sorted = (unsigned int*)((char*)d_ws + off);
    off = align_up(off + (size_t)B * CAP * 4, 256);
    bool fast = (off <= ws_size) && (B <= MAXB);

    if (fast) {
        hipMemsetAsync(delta_extra, 0, (size_t)N * sizeof(float), stream);
        init_kernel<<<(PB + 255) / 256, 256, 0, stream>>>(g_ptr64, ovf_cnt, PB);
        int chunk = (E + NB - 1) / NB;
        fused_kernel<<<NB, BLK, 0, stream>>>(x, pos, mlp_w, mlp_b, head_w,
                                             srcs, dsts, E, B, chunk,
                                             g_ptr64, sorted, ovf, ovf_cnt);
        ovf_kernel<<<16, 256, 0, stream>>>(ovf, ovf_cnt, delta_extra);
        reduce_kernel<<<B, BNODES, 0, stream>>>((const float*)x, g_ptr64, sorted,
                                                delta_extra, head_b,
                                                (float*)d_out, N);
    } else {
        float* delta = (float*)d_ws;
        hipMemsetAsync(delta, 0, (size_t)N * sizeof(float), stream);
        int edge_blocks = (E + 256 * RPT - 1) / (256 * RPT);
        edge_kernel_fallback<<<edge_blocks, 256, 0, stream>>>(
            x, pos, mlp_w, mlp_b, head_w, srcs, dsts, delta, E);
        node_kernel_fallback<<<(N + 255) / 256, 256, 0, stream>>>(
            (const float*)x, delta, head_b, (float*)d_out, N);
    }
}